// Round 5
// baseline (2442.593 us; speedup 1.0000x reference)
//
#include <hip/hip_runtime.h>
#include <hip/hip_bf16.h>

// Problem constants
#define LAYERS 12
#define NH     12
#define D      768
#define DH     64
#define FF     3072
#define NS     8
#define NV     1024
#define BB     2
#define TT     1024
#define BT     (BB*TT)          // 2048 token rows

typedef __attribute__((ext_vector_type(8))) short  short8;   // 8 bf16 (4 VGPRs)
typedef __attribute__((ext_vector_type(8))) unsigned short ushort8;
typedef __attribute__((ext_vector_type(4))) float  floatx4;  // MFMA C/D

// ---------------------------------------------------------------- utilities
__device__ __forceinline__ float wave_sum(float v) {
    v += __shfl_xor(v, 1);  v += __shfl_xor(v, 2);  v += __shfl_xor(v, 4);
    v += __shfl_xor(v, 8);  v += __shfl_xor(v, 16); v += __shfl_xor(v, 32);
    return v;
}
__device__ __forceinline__ unsigned short f2bf(float f) {
    unsigned int u = __builtin_bit_cast(unsigned int, f);
    u += 0x7fffu + ((u >> 16) & 1u);          // RNE
    return (unsigned short)(u >> 16);
}
__device__ __forceinline__ ushort8 pack8(float4 f0, float4 f1) {
    ushort8 r;
    r[0]=f2bf(f0.x); r[1]=f2bf(f0.y); r[2]=f2bf(f0.z); r[3]=f2bf(f0.w);
    r[4]=f2bf(f1.x); r[5]=f2bf(f1.y); r[6]=f2bf(f1.z); r[7]=f2bf(f1.w);
    return r;
}
// async global->LDS 16B DMA; dest = wave-uniform base + lane*16
__device__ __forceinline__ void gl2lds16(const void* g, void* l) {
    __builtin_amdgcn_global_load_lds(
        (const __attribute__((address_space(1))) unsigned int*)g,
        (__attribute__((address_space(3))) unsigned int*)l, 16, 0, 0);
}

// ---------------------------------------------------------------- fp32 -> bf16 weight convert
__global__ __launch_bounds__(256) void cvt_bf16_kernel(
    const float* __restrict__ w, unsigned short* __restrict__ o, int n8) {
    const int i = blockIdx.x * 256 + threadIdx.x;
    if (i < n8) {
        const float* p = w + (size_t)i * 8;
        float4 f0 = *(const float4*)p;
        float4 f1 = *(const float4*)(p + 4);
        *(ushort8*)(o + (size_t)i * 8) = pack8(f0, f1);
    }
}

// ---------------------------------------------------------------- embedding (fp32 x)
__global__ __launch_bounds__(256) void embed_kernel(
    const int* __restrict__ prev_tokens, const int* __restrict__ positions,
    const float* __restrict__ intent, const float* __restrict__ rvq,
    const float* __restrict__ pos_emb, float* __restrict__ x) {
    const int row = blockIdx.x;
    const int b   = row >> 10;
    __shared__ int toks[NS];
    __shared__ int p;
    if (threadIdx.x < NS) toks[threadIdx.x] = prev_tokens[row * NS + threadIdx.x];
    if (threadIdx.x == NS) p = positions[row];
    __syncthreads();
    for (int d = threadIdx.x; d < D; d += 256) {
        float acc = intent[b * D + d] + pos_emb[p * D + d];
        #pragma unroll
        for (int s = 0; s < NS; ++s)
            acc += rvq[((size_t)(s * NV + toks[s])) * D + d];
        x[(size_t)row * D + d] = acc;
    }
}

// ---------------------------------------------------------------- rmsnorm -> bf16 (wave per row)
__global__ __launch_bounds__(256) void rmsnorm_kernel(
    const float* __restrict__ x, const float* __restrict__ w, unsigned short* __restrict__ h) {
    const int row  = blockIdx.x * 4 + (threadIdx.x >> 6);
    const int lane = threadIdx.x & 63;
    const float* xr = x + (size_t)row * D;
    float4 v[3];
    #pragma unroll
    for (int c = 0; c < 3; ++c) v[c] = *(const float4*)(xr + c * 256 + lane * 4);
    float ss = 0.f;
    #pragma unroll
    for (int c = 0; c < 3; ++c)
        ss += v[c].x * v[c].x + v[c].y * v[c].y + v[c].z * v[c].z + v[c].w * v[c].w;
    ss = wave_sum(ss);
    const float inv = rsqrtf(ss * (1.0f / D) + 1e-6f);
    #pragma unroll
    for (int c = 0; c < 3; ++c) {
        float4 wv = *(const float4*)(w + c * 256 + lane * 4);
        ushort4 o;
        o.x = f2bf(v[c].x * inv * wv.x);
        o.y = f2bf(v[c].y * inv * wv.y);
        o.z = f2bf(v[c].z * inv * wv.z);
        o.w = f2bf(v[c].w * inv * wv.w);
        *(ushort4*)(h + (size_t)row * D + c * 256 + lane * 4) = o;
    }
}

// ---------------------------------------------------------------- bf16 MFMA GEMM, 128x128, BK=64
// MODE 1: bf16 qkv scatter [3][B,H,T,DH] (q scaled 0.125)
// MODE 3: fp32 atomicAdd (split-K / residual accumulate)
template <int MODE, int SPLITK>
__global__ __launch_bounds__(256) void gemm128(
    const unsigned short* __restrict__ A, const unsigned short* __restrict__ W,
    void* __restrict__ Cv, int M, int N, int K) {
    __shared__ unsigned short As[128 * 64];
    __shared__ unsigned short Ws[128 * 64];
    const int tid  = threadIdx.x;
    const int row0 = blockIdx.y * 128;
    const int col0 = blockIdx.x * 128;
    const int kchunk = K / SPLITK;
    const int kbeg = blockIdx.z * kchunk;
    const int kend = kbeg + kchunk;
    const int wv = tid >> 6, lane = tid & 63;
    const int l15 = lane & 15, quad = lane >> 4;
    const int wm = (wv & 1) * 64, wn = (wv >> 1) * 64;
    const int rb = tid >> 3;
    const int sl = tid & 7;

    floatx4 acc[4][4];
    #pragma unroll
    for (int i = 0; i < 4; ++i)
        #pragma unroll
        for (int j = 0; j < 4; ++j) acc[i][j] = (floatx4){0.f, 0.f, 0.f, 0.f};

    for (int k0 = kbeg; k0 < kend; k0 += 64) {
        __syncthreads();
        #pragma unroll
        for (int q = 0; q < 4; ++q) {
            const int r = q * 32 + rb;
            const int gsl = sl ^ (r & 7);
            gl2lds16(A + (size_t)(row0 + r) * K + k0 + gsl * 8,
                     &As[(q * 256 + wv * 64) * 8]);
            gl2lds16(W + (size_t)(col0 + r) * K + k0 + gsl * 8,
                     &Ws[(q * 256 + wv * 64) * 8]);
        }
        __syncthreads();
        #pragma unroll
        for (int ks = 0; ks < 2; ++ks) {
            short8 af[4], bf[4];
            #pragma unroll
            for (int i = 0; i < 4; ++i) {
                const int r = wm + i * 16 + l15;
                af[i] = *(const short8*)(&As[r * 64 + (((ks * 4 + quad) ^ (r & 7)) * 8)]);
            }
            #pragma unroll
            for (int j = 0; j < 4; ++j) {
                const int r = wn + j * 16 + l15;
                bf[j] = *(const short8*)(&Ws[r * 64 + (((ks * 4 + quad) ^ (r & 7)) * 8)]);
            }
            #pragma unroll
            for (int i = 0; i < 4; ++i)
                #pragma unroll
                for (int j = 0; j < 4; ++j)
                    acc[i][j] = __builtin_amdgcn_mfma_f32_16x16x32_bf16(af[i], bf[j], acc[i][j], 0, 0, 0);
        }
    }

    #pragma unroll
    for (int i = 0; i < 4; ++i) {
        #pragma unroll
        for (int j = 0; j < 4; ++j) {
            const int n = col0 + wn + j * 16 + l15;
            #pragma unroll
            for (int r = 0; r < 4; ++r) {
                const int m = row0 + wm + i * 16 + quad * 4 + r;
                const float v = acc[i][j][r];
                if (MODE == 3) {
                    atomicAdd(&((float*)Cv)[(size_t)m * N + n], v);
                } else { // MODE 1: qkv scatter
                    const int wsel = n / D;
                    const int rr = n - wsel * D;
                    const int hh = rr >> 6, dd = rr & 63;
                    const int b = m >> 10, t = m & 1023;
                    ((unsigned short*)Cv)[(size_t)wsel * (BT * D) +
                        (((size_t)(b * NH + hh)) * TT + t) * DH + dd] =
                        f2bf(wsel == 0 ? v * 0.125f : v);
                }
            }
        }
    }
}

// ---------------------------------------------------------------- fused gate/up/silu GEMM
// tile: 256 M x 64 N (both gate & up), BK=64; each wave: 64M x 64N of G and U.
__global__ __launch_bounds__(256) void gateup256(
    const unsigned short* __restrict__ A, const unsigned short* __restrict__ Wg,
    const unsigned short* __restrict__ Wu, unsigned short* __restrict__ gbf, int K) {
    __shared__ unsigned short As[256 * 64];   // 32 KB
    __shared__ unsigned short Gs[64 * 64];    // 8 KB
    __shared__ unsigned short Us[64 * 64];    // 8 KB
    const int tid  = threadIdx.x;
    const int row0 = blockIdx.y * 256;
    const int col0 = blockIdx.x * 64;
    const int wv = tid >> 6, lane = tid & 63;
    const int l15 = lane & 15, quad = lane >> 4;
    const int wm = wv * 64;                   // wave's 64 M rows
    const int rb = tid >> 3;
    const int sl = tid & 7;

    floatx4 ag[4][4], au[4][4];
    #pragma unroll
    for (int i = 0; i < 4; ++i)
        #pragma unroll
        for (int j = 0; j < 4; ++j) {
            ag[i][j] = (floatx4){0.f, 0.f, 0.f, 0.f};
            au[i][j] = (floatx4){0.f, 0.f, 0.f, 0.f};
        }

    for (int k0 = 0; k0 < K; k0 += 64) {
        __syncthreads();
        #pragma unroll
        for (int q = 0; q < 8; ++q) {   // A: 2048 chunks
            const int r = q * 32 + rb;
            const int gsl = sl ^ (r & 7);
            gl2lds16(A + (size_t)(row0 + r) * K + k0 + gsl * 8,
                     &As[(q * 256 + wv * 64) * 8]);
        }
        #pragma unroll
        for (int q = 0; q < 2; ++q) {   // G,U: 512 chunks each
            const int r = q * 32 + rb;
            const int gsl = sl ^ (r & 7);
            gl2lds16(Wg + (size_t)(col0 + r) * K + k0 + gsl * 8,
                     &Gs[(q * 256 + wv * 64) * 8]);
            gl2lds16(Wu + (size_t)(col0 + r) * K + k0 + gsl * 8,
                     &Us[(q * 256 + wv * 64) * 8]);
        }
        __syncthreads();
        #pragma unroll
        for (int ks = 0; ks < 2; ++ks) {
            short8 af[4], bg[4], bu[4];
            #pragma unroll
            for (int i = 0; i < 4; ++i) {
                const int r = wm + i * 16 + l15;
                af[i] = *(const short8*)(&As[r * 64 + (((ks * 4 + quad) ^ (r & 7)) * 8)]);
            }
            #pragma unroll
            for (int j = 0; j < 4; ++j) {
                const int r = j * 16 + l15;
                const int off = r * 64 + (((ks * 4 + quad) ^ (r & 7)) * 8);
                bg[j] = *(const short8*)(&Gs[off]);
                bu[j] = *(const short8*)(&Us[off]);
            }
            #pragma unroll
            for (int i = 0; i < 4; ++i)
                #pragma unroll
                for (int j = 0; j < 4; ++j) {
                    ag[i][j] = __builtin_amdgcn_mfma_f32_16x16x32_bf16(af[i], bg[j], ag[i][j], 0, 0, 0);
                    au[i][j] = __builtin_amdgcn_mfma_f32_16x16x32_bf16(af[i], bu[j], au[i][j], 0, 0, 0);
                }
        }
    }

    #pragma unroll
    for (int i = 0; i < 4; ++i) {
        #pragma unroll
        for (int j = 0; j < 4; ++j) {
            const int n = col0 + j * 16 + l15;
            #pragma unroll
            for (int r = 0; r < 4; ++r) {
                const int m = row0 + wm + i * 16 + quad * 4 + r;
                const float gv = ag[i][j][r], uv = au[i][j][r];
                gbf[(size_t)m * FF + n] = f2bf(gv / (1.f + __expf(-gv)) * uv);
            }
        }
    }
}

// ---------------------------------------------------------------- MFMA flash attention, BK=128
#define KP2 136   // pitch (ushort) for 128-col LDS arrays
__global__ __launch_bounds__(256) void attn_mfma(
    const unsigned short* __restrict__ qkv, unsigned short* __restrict__ obf) {
    const int bh = blockIdx.y;
    const int b = bh / NH, h = bh - b * NH;
    const int qt = blockIdx.x;
    const int q0 = qt * 64;
    const int tid = threadIdx.x;
    const int wv = tid >> 6, lane = tid & 63;
    const int l15 = lane & 15, quad = lane >> 4;

    const unsigned short* Q = qkv + (size_t)bh * TT * DH;
    const unsigned short* K = qkv + (size_t)BT * D + (size_t)bh * TT * DH;
    const unsigned short* V = qkv + 2 * (size_t)BT * D + (size_t)bh * TT * DH;

    __shared__ unsigned short Ks[128 * 64];   // 16 KB, XOR-swizzled chunks
    __shared__ unsigned short Vts[64 * KP2];  // 17 KB, [dh][k]
    __shared__ unsigned short Pa[64 * KP2];   // 17 KB, [q][k]

    short8 qf[2];
    #pragma unroll
    for (int c = 0; c < 2; ++c)
        qf[c] = *(const short8*)(Q + (size_t)(q0 + wv * 16 + l15) * DH + c * 32 + quad * 8);

    floatx4 o_acc[4];
    #pragma unroll
    for (int j = 0; j < 4; ++j) o_acc[j] = (floatx4){0.f, 0.f, 0.f, 0.f};
    float m_run[4] = {-INFINITY, -INFINITY, -INFINITY, -INFINITY};
    float l_run[4] = {0.f, 0.f, 0.f, 0.f};

    const int rb = tid >> 3, sl = tid & 7;
    const int nkt = (q0 >> 7) + 1;
    for (int kt = 0; kt < nkt; ++kt) {
        const int k0 = kt * 128;
        __syncthreads();
        // K staging via DMA, XOR-swizzled: 1024 chunks
        #pragma unroll
        for (int q = 0; q < 4; ++q) {
            const int r = q * 32 + rb;
            const int gsl = sl ^ (r & 7);
            gl2lds16(K + (size_t)(k0 + r) * DH + gsl * 8,
                     &Ks[(q * 256 + wv * 64) * 8]);
        }
        // V transpose staging via VGPR: 128 k rows
        {
            const int kp = tid & 31, chunk = tid >> 5;
            #pragma unroll
            for (int half = 0; half < 2; ++half) {
                const int kk = half * 64 + 2 * kp;
                const unsigned short* vg = V + (size_t)(k0 + kk) * DH + chunk * 8;
                ushort8 v0 = *(const ushort8*)(vg);
                ushort8 v1 = *(const ushort8*)(vg + DH);
                #pragma unroll
                for (int j = 0; j < 8; ++j) {
                    unsigned int pk = (unsigned int)v0[j] | ((unsigned int)v1[j] << 16);
                    *(unsigned int*)(&Vts[(chunk * 8 + j) * KP2 + kk]) = pk;
                }
            }
        }
        __syncthreads();

        // QK^T over 8 key n-tiles (128 keys)
        floatx4 s[8];
        #pragma unroll
        for (int j = 0; j < 8; ++j) {
            const int r = j * 16 + l15;
            short8 kb0 = *(const short8*)(&Ks[r * 64 + ((quad ^ (r & 7)) * 8)]);
            short8 kb1 = *(const short8*)(&Ks[r * 64 + (((4 + quad) ^ (r & 7)) * 8)]);
            floatx4 z = (floatx4){0.f, 0.f, 0.f, 0.f};
            z = __builtin_amdgcn_mfma_f32_16x16x32_bf16(qf[0], kb0, z, 0, 0, 0);
            s[j] = __builtin_amdgcn_mfma_f32_16x16x32_bf16(qf[1], kb1, z, 0, 0, 0);
        }
        if (kt == nkt - 1) {   // causal mask on the diagonal 128-k block
            #pragma unroll
            for (int j = 0; j < 8; ++j) {
                const int k_abs = k0 + j * 16 + l15;
                #pragma unroll
                for (int r = 0; r < 4; ++r) {
                    const int q_abs = q0 + wv * 16 + quad * 4 + r;
                    if (k_abs > q_abs) s[j][r] = -INFINITY;
                }
            }
        }
        // online softmax (one pass per 128 keys)
        #pragma unroll
        for (int r = 0; r < 4; ++r) {
            float mt = s[0][r];
            #pragma unroll
            for (int j = 1; j < 8; ++j) mt = fmaxf(mt, s[j][r]);
            mt = fmaxf(mt, __shfl_xor(mt, 1));
            mt = fmaxf(mt, __shfl_xor(mt, 2));
            mt = fmaxf(mt, __shfl_xor(mt, 4));
            mt = fmaxf(mt, __shfl_xor(mt, 8));
            const float m_new = fmaxf(m_run[r], mt);
            const float alpha = __expf(m_run[r] - m_new);
            float rs = 0.f;
            #pragma unroll
            for (int j = 0; j < 8; ++j) {
                const float p = __expf(s[j][r] - m_new);
                s[j][r] = p;
                rs += p;
            }
            rs += __shfl_xor(rs, 1);
            rs += __shfl_xor(rs, 2);
            rs += __shfl_xor(rs, 4);
            rs += __shfl_xor(rs, 8);
            l_run[r] = l_run[r] * alpha + rs;
            m_run[r] = m_new;
            #pragma unroll
            for (int jo = 0; jo < 4; ++jo) o_acc[jo][r] *= alpha;
        }
        // P -> LDS (same-wave rows; DS in-order within wave)
        #pragma unroll
        for (int j = 0; j < 8; ++j)
            #pragma unroll
            for (int r = 0; r < 4; ++r)
                Pa[(wv * 16 + quad * 4 + r) * KP2 + j * 16 + l15] = f2bf(s[j][r]);
        // PV: 4 dh-tiles x 4 k-chunks
        short8 pa[4];
        #pragma unroll
        for (int c = 0; c < 4; ++c)
            pa[c] = *(const short8*)(&Pa[(wv * 16 + l15) * KP2 + c * 32 + quad * 8]);
        #pragma unroll
        for (int j = 0; j < 4; ++j) {
            #pragma unroll
            for (int c = 0; c < 4; ++c) {
                short8 vb = *(const short8*)(&Vts[(j * 16 + l15) * KP2 + c * 32 + quad * 8]);
                o_acc[j] = __builtin_amdgcn_mfma_f32_16x16x32_bf16(pa[c], vb, o_acc[j], 0, 0, 0);
            }
        }
    }
    // write O (bf16) as (B,T,H*DH)
    #pragma unroll
    for (int j = 0; j < 4; ++j) {
        #pragma unroll
        for (int r = 0; r < 4; ++r) {
            const int t = q0 + wv * 16 + quad * 4 + r;
            const int ch = h * DH + j * 16 + l15;
            obf[((size_t)(b * TT + t)) * D + ch] = f2bf(o_acc[j][r] / l_run[r]);
        }
    }
}

// ---------------------------------------------------------------- final norm (last tokens)
__global__ __launch_bounds__(256) void final_norm_kernel(
    const float* __restrict__ x, const float* __restrict__ w, float* __restrict__ last) {
    const int b = blockIdx.x;
    const float* xr = x + ((size_t)(b * TT + (TT - 1))) * D;
    float ss = 0.f;
    for (int d = threadIdx.x; d < D; d += 256) { float v = xr[d]; ss += v * v; }
    const int wave = threadIdx.x >> 6, lane = threadIdx.x & 63;
    __shared__ float red[4];
    float s = wave_sum(ss);
    if (lane == 0) red[wave] = s;
    __syncthreads();
    float tot = red[0] + red[1] + red[2] + red[3];
    float inv = rsqrtf(tot * (1.0f / D) + 1e-6f);
    for (int d = threadIdx.x; d < D; d += 256)
        last[(size_t)b * D + d] = xr[d] * inv * w[d];
}

// ---------------------------------------------------------------- heads
__global__ __launch_bounds__(256) void heads_kernel(
    const float* __restrict__ last, const float* __restrict__ hw, float* __restrict__ out) {
    const int gw = (blockIdx.x * 256 + threadIdx.x) >> 6;
    const int lane = threadIdx.x & 63;
    const int s = gw >> 10, v = gw & 1023;
    const float* w = hw + (size_t)gw * D;
    float a0 = 0.f, a1 = 0.f;
    for (int d = lane; d < D; d += 64) {
        const float ww = w[d];
        a0 = fmaf(ww, last[d], a0);
        a1 = fmaf(ww, last[D + d], a1);
    }
    a0 = wave_sum(a0);
    a1 = wave_sum(a1);
    if (lane == 0) {
        out[((size_t)s * BB + 0) * NV + v] = a0;
        out[((size_t)s * BB + 1) * NV + v] = a1;
    }
}

// ---------------------------------------------------------------- launcher
extern "C" void kernel_launch(void* const* d_in, const int* in_sizes, int n_in,
                              void* d_out, int out_size, void* d_ws, size_t ws_size,
                              hipStream_t stream) {
    const int*   prev_tokens = (const int*)  d_in[0];
    const int*   positions   = (const int*)  d_in[1];
    const float* intent      = (const float*)d_in[2];
    const float* rvq         = (const float*)d_in[3];
    const float* pos_emb     = (const float*)d_in[4];
    const float* norm1_w     = (const float*)d_in[5];
    const float* norm2_w     = (const float*)d_in[6];
    const float* qkv_w       = (const float*)d_in[7];
    const float* proj_w      = (const float*)d_in[8];
    const float* gate_w      = (const float*)d_in[9];
    const float* up_w        = (const float*)d_in[10];
    const float* down_w      = (const float*)d_in[11];
    const float* normf_w     = (const float*)d_in[12];
    const float* heads_w     = (const float*)d_in[13];
    float* out = (float*)d_out;

    char* base = (char*)d_ws;
    float* x   = (float*)base;                       base += (size_t)BT * D * 4;
    float* last= (float*)base;                       base += 4096;
    unsigned short* hbf    = (unsigned short*)base;  base += (size_t)BT * D * 2;
    unsigned short* qkvbf  = (unsigned short*)base;  base += (size_t)3 * BT * D * 2;
    unsigned short* obf    = (unsigned short*)base;  base += (size_t)BT * D * 2;
    unsigned short* gbf    = (unsigned short*)base;  base += (size_t)BT * FF * 2;
    // bf16 weight caches
    unsigned short* wqkv = (unsigned short*)base;    base += (size_t)LAYERS * 3 * D * D * 2;
    unsigned short* wproj= (unsigned short*)base;    base += (size_t)LAYERS * D * D * 2;
    unsigned short* wgate= (unsigned short*)base;    base += (size_t)LAYERS * FF * D * 2;
    unsigned short* wup  = (unsigned short*)base;    base += (size_t)LAYERS * FF * D * 2;
    unsigned short* wdown= (unsigned short*)base;    base += (size_t)LAYERS * D * FF * 2;

    // convert weights fp32 -> bf16 (per launch; deterministic)
    {
        const int n_qkv  = LAYERS * 3 * D * D / 8;
        const int n_proj = LAYERS * D * D / 8;
        const int n_ff   = LAYERS * FF * D / 8;
        cvt_bf16_kernel<<<(n_qkv  + 255) / 256, 256, 0, stream>>>(qkv_w,  wqkv,  n_qkv);
        cvt_bf16_kernel<<<(n_proj + 255) / 256, 256, 0, stream>>>(proj_w, wproj, n_proj);
        cvt_bf16_kernel<<<(n_ff   + 255) / 256, 256, 0, stream>>>(gate_w, wgate, n_ff);
        cvt_bf16_kernel<<<(n_ff   + 255) / 256, 256, 0, stream>>>(up_w,   wup,   n_ff);
        cvt_bf16_kernel<<<(n_ff   + 255) / 256, 256, 0, stream>>>(down_w, wdown, n_ff);
    }

    embed_kernel<<<BT, 256, 0, stream>>>(prev_tokens, positions, intent, rvq, pos_emb, x);

    for (int l = 0; l < LAYERS; ++l) {
        rmsnorm_kernel<<<BT / 4, 256, 0, stream>>>(x, norm1_w + l * D, hbf);
        gemm128<1, 1><<<dim3(3 * D / 128, BT / 128, 1), 256, 0, stream>>>(
            hbf, wqkv + (size_t)l * 3 * D * D, qkvbf, BT, 3 * D, D);
        attn_mfma<<<dim3(TT / 64, BB * NH), 256, 0, stream>>>(qkvbf, obf);
        gemm128<3, 2><<<dim3(D / 128, BT / 128, 2), 256, 0, stream>>>(
            obf, wproj + (size_t)l * D * D, x, BT, D, D);
        rmsnorm_kernel<<<BT / 4, 256, 0, stream>>>(x, norm2_w + l * D, hbf);
        gateup256<<<dim3(FF / 64, BT / 256), 256, 0, stream>>>(
            hbf, wgate + (size_t)l * FF * D, wup + (size_t)l * FF * D, gbf, D);
        gemm128<3, 4><<<dim3(D / 128, BT / 128, 4), 256, 0, stream>>>(
            gbf, wdown + (size_t)l * D * FF, x, BT, D, FF);
    }

    final_norm_kernel<<<2, 256, 0, stream>>>(x, normf_w, last);
    heads_kernel<<<(NS * NV * 64) / 256, 256, 0, stream>>>(last, heads_w, out);
}